// Round 1
// baseline (753.880 us; speedup 1.0000x reference)
//
#include <hip/hip_runtime.h>
#include <cstddef>

// Problem constants (fixed by reference: b=2, c=64, h=w=80)
namespace {
constexpr int B = 2;
constexpr int C = 64;
constexpr int N = 6400;           // h*w
constexpr int NT = N / 64;        // 100 tiles of 64
constexpr int MSPLIT = 4;         // split m-loop across blocks for occupancy
constexpr int MT_PER = NT / MSPLIT; // 25
constexpr float EPS = 1e-5f;
constexpr int LS = 68;            // LDS row stride: 16B-aligned float4 rows + bank stagger
}

// g_x[b,n,i] = sum_c g_w[i,c] * x[b,c,n] + g_b[i]
__global__ __launch_bounds__(256) void gx_kernel(
    const float* __restrict__ x, const float* __restrict__ g_w,
    const float* __restrict__ g_b, float* __restrict__ g_x) {
  __shared__ float xs[64 * LS];   // [c][n]
  __shared__ float gwt[64 * LS];  // [c][i] (transposed g_w)
  const int b = blockIdx.x / NT;
  const int n0 = (blockIdx.x % NT) * 64;
  const int tid = threadIdx.x;
  const int col = tid & 63, row4 = tid >> 6;
  const int ty = tid >> 4, tx = tid & 15;
  const float* xb = x + (size_t)b * C * N;
#pragma unroll
  for (int it = 0; it < 16; ++it) {
    int r = row4 + it * 4;
    xs[r * LS + col] = xb[(size_t)r * N + n0 + col];
    gwt[col * LS + r] = g_w[r * 64 + col];  // gwt[c=col][i=r] = g_w[i,c]
  }
  __syncthreads();
  float acc[4][4];
#pragma unroll
  for (int q = 0; q < 4; ++q) {
    float gbv = g_b[tx * 4 + q];
    acc[0][q] = gbv; acc[1][q] = gbv; acc[2][q] = gbv; acc[3][q] = gbv;
  }
#pragma unroll 8
  for (int c = 0; c < 64; ++c) {
    const float4 x4 = *(const float4*)&xs[c * LS + ty * 4];   // n
    const float4 g4 = *(const float4*)&gwt[c * LS + tx * 4];  // i
    acc[0][0] += x4.x * g4.x; acc[0][1] += x4.x * g4.y; acc[0][2] += x4.x * g4.z; acc[0][3] += x4.x * g4.w;
    acc[1][0] += x4.y * g4.x; acc[1][1] += x4.y * g4.y; acc[1][2] += x4.y * g4.z; acc[1][3] += x4.y * g4.w;
    acc[2][0] += x4.z * g4.x; acc[2][1] += x4.z * g4.y; acc[2][2] += x4.z * g4.z; acc[2][3] += x4.z * g4.w;
    acc[3][0] += x4.w * g4.x; acc[3][1] += x4.w * g4.y; acc[3][2] += x4.w * g4.z; acc[3][3] += x4.w * g4.w;
  }
  float* gxb = g_x + (size_t)b * N * C;
#pragma unroll
  for (int a = 0; a < 4; ++a) {
    float4 v = make_float4(acc[a][0], acc[a][1], acc[a][2], acc[a][3]);
    *(float4*)&gxb[(size_t)(n0 + ty * 4 + a) * C + tx * 4] = v;
  }
}

// Fused: aff tile = Xn^T Xm, sigmoid -> score (global, once), emb += score_tile * gx_tile.
// Grid: (b, n-tile, m-split). emb partials summed later in y_kernel.
__global__ __launch_bounds__(256, 2) void relation_main(
    const float* __restrict__ x, const float* __restrict__ g_x,
    float* __restrict__ score, float* __restrict__ emb_p) {
  __shared__ float xn[64 * LS];  // [c][n]
  __shared__ float xm[64 * LS];  // [c][m]
  __shared__ float sc[64 * LS];  // [n][m]
  __shared__ float gx[64 * LS];  // [m][i]

  const int tid = threadIdx.x;
  const int col = tid & 63, row4 = tid >> 6;
  const int ty = tid >> 4, tx = tid & 15;

  const int b = blockIdx.x / (NT * MSPLIT);
  const int rest = blockIdx.x % (NT * MSPLIT);
  const int nt = rest / MSPLIT;
  const int ms = rest % MSPLIT;
  const int n0 = nt * 64;

  const float* xb = x + (size_t)b * C * N;
  const float* gxb = g_x + (size_t)b * N * C;
  float* scoreb = score + (size_t)b * N * N;

#pragma unroll
  for (int it = 0; it < 16; ++it) {
    int c = row4 + it * 4;
    xn[c * LS + col] = xb[(size_t)c * N + n0 + col];
  }

  float e[4][4] = {{0.f, 0.f, 0.f, 0.f}, {0.f, 0.f, 0.f, 0.f},
                   {0.f, 0.f, 0.f, 0.f}, {0.f, 0.f, 0.f, 0.f}};

  for (int j = 0; j < MT_PER; ++j) {
    const int m0 = (ms * MT_PER + j) * 64;
    __syncthreads();  // prev iter's emb reads of xm/gx done before overwrite
#pragma unroll
    for (int it = 0; it < 16; ++it) {
      int c = row4 + it * 4;
      xm[c * LS + col] = xb[(size_t)c * N + m0 + col];
      gx[c * LS + col] = gxb[(size_t)(m0 + c) * C + col];
    }
    __syncthreads();

    float s[4][4] = {{0.f, 0.f, 0.f, 0.f}, {0.f, 0.f, 0.f, 0.f},
                     {0.f, 0.f, 0.f, 0.f}, {0.f, 0.f, 0.f, 0.f}};
#pragma unroll 8
    for (int c = 0; c < 64; ++c) {
      const float4 a4 = *(const float4*)&xn[c * LS + ty * 4];
      const float4 b4 = *(const float4*)&xm[c * LS + tx * 4];
      s[0][0] += a4.x * b4.x; s[0][1] += a4.x * b4.y; s[0][2] += a4.x * b4.z; s[0][3] += a4.x * b4.w;
      s[1][0] += a4.y * b4.x; s[1][1] += a4.y * b4.y; s[1][2] += a4.y * b4.z; s[1][3] += a4.y * b4.w;
      s[2][0] += a4.z * b4.x; s[2][1] += a4.z * b4.y; s[2][2] += a4.z * b4.z; s[2][3] += a4.z * b4.w;
      s[3][0] += a4.w * b4.x; s[3][1] += a4.w * b4.y; s[3][2] += a4.w * b4.z; s[3][3] += a4.w * b4.w;
    }

#pragma unroll
    for (int a = 0; a < 4; ++a) {
      float4 v;
      v.x = 1.f / (1.f + __expf(-s[a][0]));
      v.y = 1.f / (1.f + __expf(-s[a][1]));
      v.z = 1.f / (1.f + __expf(-s[a][2]));
      v.w = 1.f / (1.f + __expf(-s[a][3]));
      const int n = n0 + ty * 4 + a;
      *(float4*)&scoreb[(size_t)n * N + m0 + tx * 4] = v;
      *(float4*)&sc[(ty * 4 + a) * LS + tx * 4] = v;
    }
    __syncthreads();

#pragma unroll 8
    for (int m = 0; m < 64; ++m) {
      const float4 g4 = *(const float4*)&gx[m * LS + tx * 4];
      const float s0 = sc[(ty * 4 + 0) * LS + m];
      const float s1 = sc[(ty * 4 + 1) * LS + m];
      const float s2 = sc[(ty * 4 + 2) * LS + m];
      const float s3 = sc[(ty * 4 + 3) * LS + m];
      e[0][0] += s0 * g4.x; e[0][1] += s0 * g4.y; e[0][2] += s0 * g4.z; e[0][3] += s0 * g4.w;
      e[1][0] += s1 * g4.x; e[1][1] += s1 * g4.y; e[1][2] += s1 * g4.z; e[1][3] += s1 * g4.w;
      e[2][0] += s2 * g4.x; e[2][1] += s2 * g4.y; e[2][2] += s2 * g4.z; e[2][3] += s2 * g4.w;
      e[3][0] += s3 * g4.x; e[3][1] += s3 * g4.y; e[3][2] += s3 * g4.z; e[3][3] += s3 * g4.w;
    }
  }

  float* ep = emb_p + ((size_t)ms * B + b) * N * C;
#pragma unroll
  for (int a = 0; a < 4; ++a) {
    float4 v = make_float4(e[a][0], e[a][1], e[a][2], e[a][3]);
    *(float4*)&ep[(size_t)(n0 + ty * 4 + a) * C + tx * 4] = v;
  }
}

// y[b,o,n] = sum_i w_w[o,i] * emb[b,n,i] + w_b[o]; emb = sum of MSPLIT partials
__global__ __launch_bounds__(256) void y_kernel(
    const float* __restrict__ emb_p, const float* __restrict__ w_w,
    const float* __restrict__ w_b, float* __restrict__ y) {
  __shared__ float embT[64 * LS];  // [i][n]
  __shared__ float wt[64 * LS];    // [i][o]
  const int b = blockIdx.x / NT;
  const int n0 = (blockIdx.x % NT) * 64;
  const int tid = threadIdx.x;
  const int col = tid & 63, row4 = tid >> 6;
  const int ty = tid >> 4, tx = tid & 15;
#pragma unroll
  for (int it = 0; it < 16; ++it) {
    int r = row4 + it * 4;
    wt[col * LS + r] = w_w[r * 64 + col];  // wt[i=col][o=r]
    float v = 0.f;
#pragma unroll
    for (int msv = 0; msv < MSPLIT; ++msv)
      v += emb_p[((size_t)msv * B + b) * N * C + (size_t)(n0 + r) * C + col];
    embT[col * LS + r] = v;  // embT[i=col][n=r]
  }
  __syncthreads();
  float acc[4][4];
#pragma unroll
  for (int a = 0; a < 4; ++a) {
    float wbv = w_b[ty * 4 + a];
    acc[a][0] = wbv; acc[a][1] = wbv; acc[a][2] = wbv; acc[a][3] = wbv;
  }
#pragma unroll 8
  for (int i = 0; i < 64; ++i) {
    const float4 w4 = *(const float4*)&wt[i * LS + ty * 4];
    const float4 e4 = *(const float4*)&embT[i * LS + tx * 4];
    acc[0][0] += w4.x * e4.x; acc[0][1] += w4.x * e4.y; acc[0][2] += w4.x * e4.z; acc[0][3] += w4.x * e4.w;
    acc[1][0] += w4.y * e4.x; acc[1][1] += w4.y * e4.y; acc[1][2] += w4.y * e4.z; acc[1][3] += w4.y * e4.w;
    acc[2][0] += w4.z * e4.x; acc[2][1] += w4.z * e4.y; acc[2][2] += w4.z * e4.z; acc[2][3] += w4.z * e4.w;
    acc[3][0] += w4.w * e4.x; acc[3][1] += w4.w * e4.y; acc[3][2] += w4.w * e4.z; acc[3][3] += w4.w * e4.w;
  }
  float* yb = y + (size_t)b * C * N;
#pragma unroll
  for (int a = 0; a < 4; ++a) {
    float4 v = make_float4(acc[a][0], acc[a][1], acc[a][2], acc[a][3]);
    *(float4*)&yb[(size_t)(ty * 4 + a) * N + n0 + tx * 4] = v;
  }
}

// Per (b,group) mean / rstd over 8 channels x N contiguous floats
__global__ __launch_bounds__(256) void stats_kernel(const float* __restrict__ y,
                                                    float* __restrict__ stats) {
  const int bg = blockIdx.x;  // b*8+g
  const float* p = y + (size_t)bg * 8 * N;
  float s = 0.f, q = 0.f;
  for (int i = threadIdx.x; i < 8 * N; i += 256) {
    float v = p[i];
    s += v; q += v * v;
  }
#pragma unroll
  for (int off = 32; off > 0; off >>= 1) {
    s += __shfl_down(s, off, 64);
    q += __shfl_down(q, off, 64);
  }
  __shared__ float ls[4], lq[4];
  const int lane = threadIdx.x & 63, wv = threadIdx.x >> 6;
  if (lane == 0) { ls[wv] = s; lq[wv] = q; }
  __syncthreads();
  if (threadIdx.x == 0) {
    float S = ls[0] + ls[1] + ls[2] + ls[3];
    float Q = lq[0] + lq[1] + lq[2] + lq[3];
    const float inv = 1.f / (float)(8 * N);
    float mean = S * inv;
    float var = Q * inv - mean * mean;
    stats[bg * 2 + 0] = mean;
    stats[bg * 2 + 1] = rsqrtf(var + EPS);
  }
}

__global__ __launch_bounds__(256) void norm_kernel(
    const float* __restrict__ y, const float* __restrict__ stats,
    const float* __restrict__ gn_w, const float* __restrict__ gn_b,
    float* __restrict__ out) {
  const int idx = blockIdx.x * 256 + threadIdx.x;
  const int e0 = idx * 4;  // < B*C*N, N%4==0 so channel constant within float4
  const int b = e0 / (C * N);
  const int c = (e0 / N) & 63;
  const int g = c >> 3;
  const float mean = stats[(b * 8 + g) * 2 + 0];
  const float rstd = stats[(b * 8 + g) * 2 + 1];
  const float w = gn_w[c] * rstd;
  const float bb = gn_b[c] - mean * w;
  float4 v = *(const float4*)&y[e0];
  v.x = v.x * w + bb; v.y = v.y * w + bb; v.z = v.z * w + bb; v.w = v.w * w + bb;
  *(float4*)&out[e0] = v;
}

extern "C" void kernel_launch(void* const* d_in, const int* in_sizes, int n_in,
                              void* d_out, int out_size, void* d_ws, size_t ws_size,
                              hipStream_t stream) {
  const float* x    = (const float*)d_in[0];
  const float* g_w  = (const float*)d_in[1];
  const float* g_b  = (const float*)d_in[2];
  const float* w_w  = (const float*)d_in[3];
  const float* w_b  = (const float*)d_in[4];
  const float* gn_w = (const float*)d_in[5];
  const float* gn_b = (const float*)d_in[6];
  (void)in_sizes; (void)n_in; (void)out_size; (void)ws_size;

  float* out   = (float*)d_out;                 // (b,c,h,w) = 819200 floats
  float* score = out + (size_t)B * C * N;       // (b,N,N)

  float* ws    = (float*)d_ws;
  float* g_x   = ws;                             // B*N*C
  float* emb_p = g_x + (size_t)B * N * C;        // MSPLIT * B*N*C
  float* y     = emb_p + (size_t)MSPLIT * B * N * C;  // B*C*N
  float* stats = y + (size_t)B * C * N;          // 32 floats

  hipLaunchKernelGGL(gx_kernel, dim3(B * NT), dim3(256), 0, stream, x, g_w, g_b, g_x);
  hipLaunchKernelGGL(relation_main, dim3(B * NT * MSPLIT), dim3(256), 0, stream,
                     x, g_x, score, emb_p);
  hipLaunchKernelGGL(y_kernel, dim3(B * NT), dim3(256), 0, stream, emb_p, w_w, w_b, y);
  hipLaunchKernelGGL(stats_kernel, dim3(B * 8), dim3(256), 0, stream, y, stats);
  hipLaunchKernelGGL(norm_kernel, dim3((B * C * N) / 1024), dim3(256), 0, stream,
                     y, stats, gn_w, gn_b, out);
}

// Round 2
// 433.862 us; speedup vs baseline: 1.7376x; 1.7376x over previous
//
#include <hip/hip_runtime.h>
#include <cstddef>

namespace {
constexpr int B = 2;
constexpr int C = 64;
constexpr int N = 6400;             // h*w
constexpr int NT = N / 64;          // 100 tiles of 64
constexpr int MSPLIT = 5;           // m-range split: 1000 blocks, 20 iters each
constexpr int MT_PER = NT / MSPLIT; // 20
constexpr float EPS = 1e-5f;
constexpr int LS = 68;              // fp32 LDS row stride (pad)
constexpr int LSB = 72;             // bf16 LDS row stride (pad, 16B-aligned rows)
}

typedef __attribute__((ext_vector_type(8))) short short8;     // 8 bf16 = 4 VGPR (MFMA A/B frag)
typedef __attribute__((ext_vector_type(4))) float f32x4;      // MFMA C/D frag
typedef __attribute__((ext_vector_type(4))) unsigned short us4v;
typedef __attribute__((ext_vector_type(8))) unsigned short us8v;

__device__ inline unsigned short f2bf(float f) {  // RNE float->bf16
  unsigned int u = __float_as_uint(f);
  u += 0x7fffu + ((u >> 16) & 1u);
  return (unsigned short)(u >> 16);
}
__device__ inline float bf2f(unsigned short u) {
  return __uint_as_float(((unsigned int)u) << 16);
}

// One pass over x: produce xT[b][n][c] (bf16) and gxT[b][i][m] = (g_w.x + g_b) (bf16)
__global__ __launch_bounds__(256) void xprep_kernel(
    const float* __restrict__ x, const float* __restrict__ g_w,
    const float* __restrict__ g_b, unsigned short* __restrict__ xT,
    unsigned short* __restrict__ gxT) {
  __shared__ float xs[64 * LS];   // [c][m]
  __shared__ float gwt[64 * LS];  // [c][i]
  const int b = blockIdx.x / NT;
  const int n0 = (blockIdx.x % NT) * 64;
  const int tid = threadIdx.x;
  const int col = tid & 63, row4 = tid >> 6;
  const float* xb = x + (size_t)b * C * N;
#pragma unroll
  for (int it = 0; it < 16; ++it) {
    int r = row4 + it * 4;
    xs[r * LS + col] = xb[(size_t)r * N + n0 + col];
    gwt[col * LS + r] = g_w[r * 64 + col];  // gwt[c][i] = g_w[i][c]
  }
  __syncthreads();

  // gxT tile: rows i, cols m
  {
    const int ty = tid >> 4, tx = tid & 15;  // ty: i-group, tx: m-group
    float acc[4][4];
#pragma unroll
    for (int a = 0; a < 4; ++a) {
      float gbv = g_b[ty * 4 + a];
      acc[a][0] = gbv; acc[a][1] = gbv; acc[a][2] = gbv; acc[a][3] = gbv;
    }
#pragma unroll 8
    for (int c = 0; c < 64; ++c) {
      const f32x4 a4 = *(const f32x4*)&gwt[c * LS + ty * 4];  // i
      const f32x4 b4 = *(const f32x4*)&xs[c * LS + tx * 4];   // m
#pragma unroll
      for (int a = 0; a < 4; ++a) {
        acc[a][0] += a4[a] * b4[0]; acc[a][1] += a4[a] * b4[1];
        acc[a][2] += a4[a] * b4[2]; acc[a][3] += a4[a] * b4[3];
      }
    }
    unsigned short* gxTb = gxT + (size_t)b * 64 * N;
#pragma unroll
    for (int a = 0; a < 4; ++a) {
      us4v v;
      v[0] = f2bf(acc[a][0]); v[1] = f2bf(acc[a][1]);
      v[2] = f2bf(acc[a][2]); v[3] = f2bf(acc[a][3]);
      *(us4v*)&gxTb[(size_t)(ty * 4 + a) * N + n0 + tx * 4] = v;
    }
  }

  // xT tile: rows n (spatial), cols c — transpose out of xs
  {
    const int nloc = tid >> 2, cs = (tid & 3) * 16;
    us8v u0, u1;
#pragma unroll
    for (int j = 0; j < 8; ++j) u0[j] = f2bf(xs[(cs + j) * LS + nloc]);
#pragma unroll
    for (int j = 0; j < 8; ++j) u1[j] = f2bf(xs[(cs + 8 + j) * LS + nloc]);
    unsigned short* xTb = xT + (size_t)b * N * 64;
    *(us8v*)&xTb[(size_t)(n0 + nloc) * 64 + cs] = u0;
    *(us8v*)&xTb[(size_t)(n0 + nloc) * 64 + cs + 8] = u1;
  }
}

// MFMA relation: aff=Xn^T.Xm (bf16 mfma) -> sigmoid -> score(global fp32, via LDS)
// -> emb += sc.g_x (bf16 mfma). Grid: b x n-tile x m-split.
__global__ __launch_bounds__(256, 4) void relation_main(
    const unsigned short* __restrict__ xT, const unsigned short* __restrict__ gxT,
    float* __restrict__ score, float* __restrict__ emb_p) {
  __shared__ alignas(16) unsigned short xnT[64 * LSB];  // [n][c]
  __shared__ alignas(16) unsigned short xmT[64 * LSB];  // [m][c]
  __shared__ alignas(16) unsigned short gxt[64 * LSB];  // [i][m]
  __shared__ alignas(16) unsigned short sc[64 * LSB];   // [n][m]

  const int tid = threadIdx.x;
  const int w = tid >> 6, lane = tid & 63;
  const int l15 = lane & 15, quad = lane >> 4;

  const int bIdx = blockIdx.x / (NT * MSPLIT);
  const int rest = blockIdx.x % (NT * MSPLIT);
  const int nt = rest / MSPLIT;
  const int ms = rest % MSPLIT;
  const int n0 = nt * 64;

  const unsigned short* xTb = xT + (size_t)bIdx * N * 64;
  const unsigned short* gxTb = gxT + (size_t)bIdx * 64 * N;
  float* scoreb = score + (size_t)bIdx * N * N;

  // stage this block's n-rows once
#pragma unroll
  for (int k = 0; k < 2; ++k) {
    int ch = tid + k * 256;
    int row = ch >> 3, co = (ch & 7) * 8;
    *(us8v*)&xnT[row * LSB + co] = *(const us8v*)&xTb[(size_t)(n0 + row) * 64 + co];
  }

  f32x4 e[4];  // emb accumulator: 4 i-subtiles x (4 rows/lane)
  const f32x4 zero = {0.f, 0.f, 0.f, 0.f};
#pragma unroll
  for (int is = 0; is < 4; ++is) e[is] = zero;

  for (int j = 0; j < MT_PER; ++j) {
    const int m0 = (ms * MT_PER + j) * 64;
    __syncthreads();  // prev iter's reads of xmT/gxt/sc done
#pragma unroll
    for (int k = 0; k < 2; ++k) {
      int ch = tid + k * 256;
      int row = ch >> 3, co = (ch & 7) * 8;
      *(us8v*)&xmT[row * LSB + co] = *(const us8v*)&xTb[(size_t)(m0 + row) * 64 + co];
      *(us8v*)&gxt[row * LSB + co] = *(const us8v*)&gxTb[(size_t)row * N + m0 + co];
    }
    __syncthreads();

    // aff = Xn^T Xm for this wave's 16 n-rows x all 64 m
    short8 a0 = *(const short8*)&xnT[(16 * w + l15) * LSB + 0 * 32 + quad * 8];
    short8 a1 = *(const short8*)&xnT[(16 * w + l15) * LSB + 1 * 32 + quad * 8];
    f32x4 s[4];
#pragma unroll
    for (int msub = 0; msub < 4; ++msub) {
      short8 b0 = *(const short8*)&xmT[(16 * msub + l15) * LSB + 0 * 32 + quad * 8];
      short8 b1 = *(const short8*)&xmT[(16 * msub + l15) * LSB + 1 * 32 + quad * 8];
      f32x4 d = __builtin_amdgcn_mfma_f32_16x16x32_bf16(a0, b0, zero, 0, 0, 0);
      s[msub] = __builtin_amdgcn_mfma_f32_16x16x32_bf16(a1, b1, d, 0, 0, 0);
    }

    // sigmoid -> sc (bf16, D-layout scatter: row = quad*4+r, col = l15)
#pragma unroll
    for (int msub = 0; msub < 4; ++msub) {
#pragma unroll
      for (int r = 0; r < 4; ++r) {
        float t = __builtin_amdgcn_exp2f(-1.442695041f * s[msub][r]);
        float sig = __builtin_amdgcn_rcpf(1.f + t);
        sc[(16 * w + quad * 4 + r) * LSB + 16 * msub + l15] = f2bf(sig);
      }
    }

    // emb += sc . gxt  (same-wave LDS RAW: compiler inserts lgkmcnt wait)
    short8 p0 = *(const short8*)&sc[(16 * w + l15) * LSB + 0 * 32 + quad * 8];
    short8 p1 = *(const short8*)&sc[(16 * w + l15) * LSB + 1 * 32 + quad * 8];
#pragma unroll
    for (int is = 0; is < 4; ++is) {
      short8 g0 = *(const short8*)&gxt[(16 * is + l15) * LSB + 0 * 32 + quad * 8];
      short8 g1 = *(const short8*)&gxt[(16 * is + l15) * LSB + 1 * 32 + quad * 8];
      e[is] = __builtin_amdgcn_mfma_f32_16x16x32_bf16(p0, g0, e[is], 0, 0, 0);
      e[is] = __builtin_amdgcn_mfma_f32_16x16x32_bf16(p1, g1, e[is], 0, 0, 0);
    }

    __syncthreads();  // all sc writes visible

    // coalesced fp32 score write from sc
    {
      const int srow = tid >> 2, scg = (tid & 3) * 16;
      us8v u0 = *(const us8v*)&sc[srow * LSB + scg];
      us8v u1 = *(const us8v*)&sc[srow * LSB + scg + 8];
      float* sp = scoreb + (size_t)(n0 + srow) * N + m0 + scg;
      f32x4 v;
      v[0] = bf2f(u0[0]); v[1] = bf2f(u0[1]); v[2] = bf2f(u0[2]); v[3] = bf2f(u0[3]);
      *(f32x4*)&sp[0] = v;
      v[0] = bf2f(u0[4]); v[1] = bf2f(u0[5]); v[2] = bf2f(u0[6]); v[3] = bf2f(u0[7]);
      *(f32x4*)&sp[4] = v;
      v[0] = bf2f(u1[0]); v[1] = bf2f(u1[1]); v[2] = bf2f(u1[2]); v[3] = bf2f(u1[3]);
      *(f32x4*)&sp[8] = v;
      v[0] = bf2f(u1[4]); v[1] = bf2f(u1[5]); v[2] = bf2f(u1[6]); v[3] = bf2f(u1[7]);
      *(f32x4*)&sp[12] = v;
    }
  }

  // emb partial store (fp32): emb_p[ms][b][n][i]
  float* ep = emb_p + ((size_t)ms * B + bIdx) * (size_t)N * 64;
#pragma unroll
  for (int is = 0; is < 4; ++is) {
#pragma unroll
    for (int r = 0; r < 4; ++r) {
      ep[(size_t)(n0 + 16 * w + quad * 4 + r) * 64 + 16 * is + l15] = e[is][r];
    }
  }
}

// y[b,o,n] = sum_i w_w[o,i] * emb[b,n,i] + w_b[o]; emb = sum of MSPLIT partials
__global__ __launch_bounds__(256) void y_kernel(
    const float* __restrict__ emb_p, const float* __restrict__ w_w,
    const float* __restrict__ w_b, float* __restrict__ y) {
  __shared__ float embT[64 * LS];  // [i][n]
  __shared__ float wt[64 * LS];    // [i][o]
  const int b = blockIdx.x / NT;
  const int n0 = (blockIdx.x % NT) * 64;
  const int tid = threadIdx.x;
  const int col = tid & 63, row4 = tid >> 6;
  const int ty = tid >> 4, tx = tid & 15;
#pragma unroll
  for (int it = 0; it < 16; ++it) {
    int r = row4 + it * 4;
    wt[col * LS + r] = w_w[r * 64 + col];
    float v = 0.f;
#pragma unroll
    for (int msv = 0; msv < MSPLIT; ++msv)
      v += emb_p[((size_t)msv * B + b) * N * C + (size_t)(n0 + r) * C + col];
    embT[col * LS + r] = v;
  }
  __syncthreads();
  float acc[4][4];
#pragma unroll
  for (int a = 0; a < 4; ++a) {
    float wbv = w_b[ty * 4 + a];
    acc[a][0] = wbv; acc[a][1] = wbv; acc[a][2] = wbv; acc[a][3] = wbv;
  }
#pragma unroll 8
  for (int i = 0; i < 64; ++i) {
    const f32x4 w4 = *(const f32x4*)&wt[i * LS + ty * 4];
    const f32x4 e4 = *(const f32x4*)&embT[i * LS + tx * 4];
#pragma unroll
    for (int a = 0; a < 4; ++a) {
      acc[a][0] += w4[a] * e4[0]; acc[a][1] += w4[a] * e4[1];
      acc[a][2] += w4[a] * e4[2]; acc[a][3] += w4[a] * e4[3];
    }
  }
  float* yb = y + (size_t)b * C * N;
#pragma unroll
  for (int a = 0; a < 4; ++a) {
    f32x4 v = {acc[a][0], acc[a][1], acc[a][2], acc[a][3]};
    *(f32x4*)&yb[(size_t)(ty * 4 + a) * N + n0 + tx * 4] = v;
  }
}

__global__ __launch_bounds__(256) void stats_kernel(const float* __restrict__ y,
                                                    float* __restrict__ stats) {
  const int bg = blockIdx.x;  // b*8+g
  const f32x4* p = (const f32x4*)(y + (size_t)bg * 8 * N);
  float s = 0.f, q = 0.f;
  for (int i = threadIdx.x; i < 8 * N / 4; i += 256) {
    f32x4 v = p[i];
    s += v[0] + v[1] + v[2] + v[3];
    q += v[0] * v[0] + v[1] * v[1] + v[2] * v[2] + v[3] * v[3];
  }
#pragma unroll
  for (int off = 32; off > 0; off >>= 1) {
    s += __shfl_down(s, off, 64);
    q += __shfl_down(q, off, 64);
  }
  __shared__ float ls[4], lq[4];
  const int lane = threadIdx.x & 63, wv = threadIdx.x >> 6;
  if (lane == 0) { ls[wv] = s; lq[wv] = q; }
  __syncthreads();
  if (threadIdx.x == 0) {
    float S = ls[0] + ls[1] + ls[2] + ls[3];
    float Q = lq[0] + lq[1] + lq[2] + lq[3];
    const float inv = 1.f / (float)(8 * N);
    float mean = S * inv;
    float var = Q * inv - mean * mean;
    stats[bg * 2 + 0] = mean;
    stats[bg * 2 + 1] = rsqrtf(var + EPS);
  }
}

__global__ __launch_bounds__(256) void norm_kernel(
    const float* __restrict__ y, const float* __restrict__ stats,
    const float* __restrict__ gn_w, const float* __restrict__ gn_b,
    float* __restrict__ out) {
  const int idx = blockIdx.x * 256 + threadIdx.x;
  const int e0 = idx * 4;
  const int b = e0 / (C * N);
  const int c = (e0 / N) & 63;
  const int g = c >> 3;
  const float mean = stats[(b * 8 + g) * 2 + 0];
  const float rstd = stats[(b * 8 + g) * 2 + 1];
  const float w = gn_w[c] * rstd;
  const float bb = gn_b[c] - mean * w;
  f32x4 v = *(const f32x4*)&y[e0];
  v[0] = v[0] * w + bb; v[1] = v[1] * w + bb;
  v[2] = v[2] * w + bb; v[3] = v[3] * w + bb;
  *(f32x4*)&out[e0] = v;
}

extern "C" void kernel_launch(void* const* d_in, const int* in_sizes, int n_in,
                              void* d_out, int out_size, void* d_ws, size_t ws_size,
                              hipStream_t stream) {
  const float* x    = (const float*)d_in[0];
  const float* g_w  = (const float*)d_in[1];
  const float* g_b  = (const float*)d_in[2];
  const float* w_w  = (const float*)d_in[3];
  const float* w_b  = (const float*)d_in[4];
  const float* gn_w = (const float*)d_in[5];
  const float* gn_b = (const float*)d_in[6];
  (void)in_sizes; (void)n_in; (void)out_size; (void)ws_size;

  float* out   = (float*)d_out;
  float* score = out + (size_t)B * C * N;

  float* ws    = (float*)d_ws;
  float* emb_p = ws;                                       // MSPLIT*B*N*C fp32
  float* y     = emb_p + (size_t)MSPLIT * B * N * C;       // B*C*N fp32
  float* stats = y + (size_t)B * C * N;                    // 32 fp32
  unsigned short* xT  = (unsigned short*)(stats + 32);     // B*N*64 bf16
  unsigned short* gxT = xT + (size_t)B * N * 64;           // B*64*N bf16

  hipLaunchKernelGGL(xprep_kernel, dim3(B * NT), dim3(256), 0, stream,
                     x, g_w, g_b, xT, gxT);
  hipLaunchKernelGGL(relation_main, dim3(B * NT * MSPLIT), dim3(256), 0, stream,
                     xT, gxT, score, emb_p);
  hipLaunchKernelGGL(y_kernel, dim3(B * NT), dim3(256), 0, stream, emb_p, w_w, w_b, y);
  hipLaunchKernelGGL(stats_kernel, dim3(B * 8), dim3(256), 0, stream, y, stats);
  hipLaunchKernelGGL(norm_kernel, dim3((B * C * N) / 1024), dim3(256), 0, stream,
                     y, stats, gn_w, gn_b, out);
}